// Round 2
// baseline (26745.221 us; speedup 1.0000x reference)
//
#include <hip/hip_runtime.h>

// ---- problem constants ----
#define RPB 4            // batch rows per block
// ws layout (float offsets)
#define WS_WCAT   0                       // scan1 gates W: [96][1024][4] k4-tiled, col=u*4+q
#define WS_LINT   (WS_WCAT + 96*4096)     // scan1 lin  W: [40][1024][4] k4-tiled, col=s*8+n
#define WS_BZ     (WS_LINT + 40*4096)     // [1024] combined wlstm bias, col=u*4+q
#define WS_LINB   (WS_BZ + 1024)          // [1024] lin_b, col = s*8+n
#define WS_MU0    (WS_LINB + 1024)        // [128]
#define WS_SEXP   (WS_MU0 + 128)          // [128] exp(0.5*ls0)
#define WS_RNNT   (WS_SEXP + 128)         // scan2 gates W: [128][1024][4] k4-tiled
#define WS_BRNN   (WS_RNNT + 128*4096)    // [1024]
#define WS_PPT1   (WS_BRNN + 1024)        // [24][256][4] k4-tiled
#define WS_PPT2   (WS_PPT1 + 24*1024)     // [64][256][4] k4-tiled

// out offsets (return order, flat)
#define OUT_OBS_MU 0
#define OUT_OBS_S  (256*1024*64)
#define OUT_HPOST  (2*256*1024*64)
#define OUT_CPOST  (OUT_HPOST + 1024*256)
#define OUT_WH     (OUT_CPOST + 1024*256)
#define OUT_WC     (OUT_WH + 1024*256)
#define OUT_WMAP   (OUT_WC + 1024*256)

__device__ __forceinline__ float sigm(float x){ return 1.0f/(1.0f+__expf(-x)); }
// overflow-safe tanh
__device__ __forceinline__ float tanhf_fast(float x){ return 2.0f/(1.0f+__expf(-2.0f*x)) - 1.0f; }

// ---------------- prep kernels ----------------
__global__ void prep_wcat(const float* __restrict__ Wih, const float* __restrict__ Whh,
                          float* __restrict__ ws){
    int idx = blockIdx.x*256 + threadIdx.x;          // < 96*4096
    int k4 = idx >> 12, rem = idx & 4095;
    int col = rem >> 2, j = rem & 3;
    int k = (k4 << 2) | j;
    int u = col >> 2, q = col & 3;                   // PyTorch gate order i,f,g,o
    float v = (k < 128) ? Wih[(q*256+u)*128 + k] : Whh[(q*256+u)*256 + (k-128)];
    ws[WS_WCAT + idx] = v;
}
__global__ void prep_lin(const float* __restrict__ lin_W, float* __restrict__ ws){
    int idx = blockIdx.x*256 + threadIdx.x;          // < 40*4096
    int k4 = idx >> 12, rem = idx & 4095;
    int col = rem >> 2, j = rem & 3;
    int k = (k4 << 2) | j;
    int s = col >> 3, n = col & 7;
    ws[WS_LINT + idx] = lin_W[(n*128 + s)*160 + k];
}
__global__ void prep_rnn(const float* __restrict__ Wih, const float* __restrict__ Whh,
                         float* __restrict__ ws){
    int idx = blockIdx.x*256 + threadIdx.x;          // < 128*4096
    int k4 = idx >> 12, rem = idx & 4095;
    int col = rem >> 2, j = rem & 3;
    int k = (k4 << 2) | j;
    int u = col >> 2, q = col & 3;
    float v = (k < 256) ? Wih[(q*256+u)*256 + k] : Whh[(q*256+u)*256 + (k-256)];
    ws[WS_RNNT + idx] = v;
}
__global__ void prep_bias(const float* __restrict__ wbih, const float* __restrict__ wbhh,
                          const float* __restrict__ rbih, const float* __restrict__ rbhh,
                          const float* __restrict__ lin_b, float* __restrict__ ws){
    int idx = blockIdx.x*256 + threadIdx.x;          // < 1024
    int u = idx >> 2, q = idx & 3;
    ws[WS_BZ + idx]   = wbih[q*256+u] + wbhh[q*256+u];
    ws[WS_BRNN + idx] = rbih[q*256+u] + rbhh[q*256+u];
    int s = idx >> 3, n = idx & 7;
    ws[WS_LINB + idx] = lin_b[n*128 + s];
}
__global__ void prep_pp(const float* __restrict__ W1, const float* __restrict__ W2,
                        float* __restrict__ ws){
    int idx = blockIdx.x*256 + threadIdx.x;          // < 24*1024 + 64*1024
    if (idx < 24*1024){
        int k4 = idx >> 10, rem = idx & 1023;
        int i = rem >> 2, j = rem & 3;
        ws[WS_PPT1 + idx] = W1[i*96 + (k4*4 + j)];
    } else {
        int kk = idx - 24*1024;
        int k4 = kk >> 10, rem = kk & 1023;
        int i = rem >> 2, j = rem & 3;
        ws[WS_PPT2 + kk] = W2[i*256 + (k4*4 + j)];
    }
}
// initial DBlock on the single broadcast h0 row
__global__ void dblock0(const float* __restrict__ h0,
                        const float* __restrict__ W1, const float* __restrict__ b1,
                        const float* __restrict__ W2, const float* __restrict__ b2,
                        const float* __restrict__ Wmu, const float* __restrict__ bmu,
                        const float* __restrict__ Wls, const float* __restrict__ bls,
                        float* __restrict__ ws){
    __shared__ float s_t[512];
    __shared__ float s_h[256];
    int tid = threadIdx.x;                            // 512 threads
    if (tid < 256) s_h[tid] = h0[tid];
    __syncthreads();
    {
        float a = b1[tid], b = b2[tid];
        for (int i=0;i<256;i++){ float h = s_h[i]; a += h*W1[tid*256+i]; b += h*W2[tid*256+i]; }
        s_t[tid] = tanhf_fast(a)*sigm(b);
    }
    __syncthreads();
    if (tid < 128){
        float m = bmu[tid];
        for (int k=0;k<512;k++) m += s_t[k]*Wmu[tid*512+k];
        ws[WS_MU0 + tid] = m;
    } else if (tid < 256){
        int j = tid - 128;
        float l = bls[j];
        for (int k=0;k<512;k++) l += s_t[k]*Wls[j*512+k];
        ws[WS_SEXP + j] = __expf(0.5f*l);
    }
}

// ---------------- fused scan: both recurrences, one dispatch ----------------
// 256 blocks x 1024 threads. obs never leaves LDS; LSTM cells and the
// softmax-combine run in registers via 4-/8-lane shuffles (gate q and mixture n
// are adjacent lanes of the GEMV column layout), removing the s_g/s_mus LDS
// round-trips and their bank conflicts. 9 barriers/step.
__global__ __launch_bounds__(1024, 4) void scan_fused(
    const float* __restrict__ ext, const float* __restrict__ eps_init,
    const float* __restrict__ eps_seq, const float* __restrict__ eps_obs,
    const float* __restrict__ dyn_h0, const float* __restrict__ posterior_h0,
    const float* __restrict__ wl_W, const float* __restrict__ wl_b,
    const float* __restrict__ dyn_logsigma,
    const float* __restrict__ est_logdelta, const float* __restrict__ est_H,
    const float* __restrict__ est_b,
    const float* __restrict__ pp_b1, const float* __restrict__ pp_b2,
    const float* __restrict__ ws, float* __restrict__ out)
{
    const int tid  = threadIdx.x;
    const int lane = tid & 63;
    const int b4   = lane & ~3;          // base of 4-lane gate group
    const int r0   = blockIdx.x * RPB;
    const int u    = tid >> 2, q = tid & 3;   // gates column mapping col=u*4+q

    __shared__ __align__(16) float s_x[RPB][384];    // [state(128) | h_w(256)]
    __shared__ __align__(16) float s_xc[RPB][160];   // [state(128) | u(t+?)(32)]
    __shared__ __align__(16) float s_v[RPB][512];    // [px(256) | h_post(256)]
    __shared__ __align__(16) float s_ax[RPB][96];    // [u(t)(32) | obs_s(t)(64)]
    __shared__ __align__(16) float s_l1[RPB][256];
    __shared__ __align__(16) float s_HT[128][64];    // H^T [s][o]
    __shared__ __align__(16) float s_wlW[2048];
    __shared__ float s_pe[4][RPB][64];               // emission split-K partials
    __shared__ float s_wlog[RPB][8];
    __shared__ float s_dstd[128];
    __shared__ float s_ostd[64], s_eb[64], s_wlb[8];

    for (int idx = tid; idx < 128*64; idx += 1024){
        int s = idx >> 6, o = idx & 63;
        s_HT[s][o] = est_H[o*128 + s];
    }
    for (int idx = tid; idx < 2048; idx += 1024) s_wlW[idx] = wl_W[idx];
    if (tid < 128) s_dstd[tid] = __expf(0.5f*dyn_logsigma[tid]);
    if (tid < 64){ s_ostd[tid] = __expf(0.5f*est_logdelta[tid]); s_eb[tid] = est_b[tid]; }
    if (tid < 8) s_wlb[tid] = wl_b[tid];
    if (tid < 128){
        float m = ws[WS_MU0+tid], sd = ws[WS_SEXP+tid];
        #pragma unroll
        for (int r=0;r<RPB;r++){
            float v = m + sd*eps_init[(r0+r)*128 + tid];
            s_x[r][tid] = v; s_xc[r][tid] = v;
        }
    }
    if (tid < 256){
        float h0v = dyn_h0[tid], hp = posterior_h0[tid];
        #pragma unroll
        for (int r=0;r<RPB;r++){ s_x[r][128+tid] = h0v; s_v[r][256+tid] = hp; }
    }
    if (tid < 128){                          // stage u(0) for the first mus GEMV
        int r = tid >> 5, ii = tid & 31;
        s_xc[r][128+ii] = ext[(r0+r)*32 + ii];
    }
    float c1[RPB], c2[RPB];
    #pragma unroll
    for (int r=0;r<RPB;r++){ c1[r] = 0.0f; c2[r] = 0.0f; }

    const float bz  = ws[WS_BZ + tid];
    const float lb  = ws[WS_LINB + tid];
    const float brz = ws[WS_BRNN + tid];
    const float b1v = pp_b1[tid & 255];
    const float b2v = pp_b2[tid & 255];
    const float4* __restrict__ Wg  = (const float4*)(ws + WS_WCAT);
    const float4* __restrict__ Lg  = (const float4*)(ws + WS_LINT);
    const float4* __restrict__ Rg  = (const float4*)(ws + WS_RNNT);
    const float4* __restrict__ T1g = (const float4*)(ws + WS_PPT1);
    const float4* __restrict__ T2g = (const float4*)(ws + WS_PPT2);
    __syncthreads();

    for (int t = 0; t < 256; t++){
        // ---- A: gates1 GEMV (K=384) + mus GEMV (K=160), results stay in regs ----
        float ac[RPB], am[RPB];
        #pragma unroll
        for (int r=0;r<RPB;r++){ ac[r] = bz; am[r] = lb; }
        #pragma unroll 4
        for (int i4 = 0; i4 < 96; i4++){
            float4 w = Wg[i4*1024 + tid];
            #pragma unroll
            for (int r=0;r<RPB;r++){
                float4 xv = ((const float4*)s_x[r])[i4];
                ac[r] += xv.x*w.x + xv.y*w.y + xv.z*w.z + xv.w*w.w;
            }
        }
        #pragma unroll 4
        for (int i4 = 0; i4 < 40; i4++){
            float4 w = Lg[i4*1024 + tid];
            #pragma unroll
            for (int r=0;r<RPB;r++){
                float4 xv = ((const float4*)s_xc[r])[i4];
                am[r] += xv.x*w.x + xv.y*w.y + xv.z*w.z + xv.w*w.w;
            }
        }
        __syncthreads();                                 // BAR1

        // ---- B: cell1 in registers (4-lane shuffle); q==0 writes h ----
        #pragma unroll
        for (int r=0;r<RPB;r++){
            float pre = ac[r];
            float e  = __expf((q==2 ? -2.0f : -1.0f)*pre);
            float a_ = (q==2) ? (2.0f/(1.0f+e) - 1.0f) : (1.0f/(1.0f+e));
            float iv = __shfl(a_, b4+0);
            float fv = __shfl(a_, b4+1);
            float gv = __shfl(a_, b4+2);
            float ov = __shfl(a_, b4+3);
            float c  = fv*c1[r] + iv*gv;
            c1[r] = c;
            if (q == 0) s_x[r][128+u] = ov*tanhf_fast(c);
        }
        if (tid < 128){                        // copy u(t) for MLP1's ax
            int r = tid >> 5, ii = tid & 31;
            s_ax[r][ii] = s_xc[r][128+ii];
        }
        __syncthreads();                                 // BAR2

        // ---- C: wl logits, split-K over 32 lanes ----
        {
            int rr = tid >> 8, n = (tid >> 5) & 7, part = tid & 31;
            const float* wrow = &s_wlW[n*256 + part*8];
            const float* hrow = &s_x[rr][128 + part*8];
            float p = 0.f;
            #pragma unroll
            for (int ii=0; ii<8; ii++) p += hrow[ii]*wrow[ii];
            p += __shfl_xor(p, 1);
            p += __shfl_xor(p, 2);
            p += __shfl_xor(p, 4);
            p += __shfl_xor(p, 8);
            p += __shfl_xor(p, 16);
            if (part == 0) s_wlog[rr][n] = p + s_wlb[n];
        }
        __syncthreads();                                 // BAR3

        // ---- E: softmax in 8-lane group + weighted combine + resample ----
        {
            int s = tid >> 3, n = tid & 7;
            #pragma unroll
            for (int r=0;r<RPB;r++){
                float lg = s_wlog[r][n];
                float mx = lg;
                mx = fmaxf(mx, __shfl_xor(mx, 1));
                mx = fmaxf(mx, __shfl_xor(mx, 2));
                mx = fmaxf(mx, __shfl_xor(mx, 4));
                float e = __expf(lg - mx);
                float sm = e;
                sm += __shfl_xor(sm, 1);
                sm += __shfl_xor(sm, 2);
                sm += __shfl_xor(sm, 4);
                float w = __fdividef(e, sm);
                if (s == 0)                               // tid<8: wmap out
                    out[OUT_WMAP + (t*1024 + r0 + r)*8 + n] = w;
                float p = am[r]*w;
                p += __shfl_xor(p, 1);
                p += __shfl_xor(p, 2);
                p += __shfl_xor(p, 4);
                if (n == 0){
                    float st = p + s_dstd[s]*eps_seq[(t*1024 + r0 + r)*128 + s];
                    s_x[r][s] = st; s_xc[r][s] = st;
                }
            }
            if (t < 255 && tid < 128){                    // stage u(t+1) for mus
                int r = tid >> 5, ii = tid & 31;
                s_xc[r][128+ii] = ext[((t+1)*1024 + r0 + r)*32 + ii];
            }
        }
        __syncthreads();                                 // BAR4

        // ---- F: emission partials (split-K=4) ----
        {
            int o = tid & 63, rr = (tid >> 6) & 3, kq = tid >> 8;
            const float* xrow = &s_x[rr][kq*32];
            float a = 0.f;
            #pragma unroll
            for (int k=0;k<32;k++) a += xrow[k]*s_HT[kq*32+k][o];
            s_pe[kq][rr][o] = a;
        }
        __syncthreads();                                 // BAR5

        // ---- G: emission reduce; obs to out AND into s_ax for the MLP ----
        if (tid < 256){
            int o = tid & 63, rr = tid >> 6;
            float a = s_eb[o] + s_pe[0][rr][o] + s_pe[1][rr][o]
                    + s_pe[2][rr][o] + s_pe[3][rr][o];
            int base = (t*1024 + r0 + rr)*64 + o;
            out[OUT_OBS_MU + base] = a;
            float os = a + s_ostd[o]*eps_obs[base];
            out[OUT_OBS_S + base] = os;
            s_ax[rr][32+o] = os;
        }
        __syncthreads();                                 // BAR6

        // ---- H: MLP layer 1 (thread = (i, r), K=96) ----
        {
            int i = tid & 255, rr = tid >> 8;
            float l1 = b1v;
            #pragma unroll 4
            for (int k4=0; k4<24; k4++){
                float4 w  = T1g[k4*256 + i];
                float4 xv = ((const float4*)s_ax[rr])[k4];
                l1 += xv.x*w.x + xv.y*w.y + xv.z*w.z + xv.w*w.w;
            }
            s_l1[rr][i] = fmaxf(l1, 0.f);
        }
        __syncthreads();                                 // BAR7

        // ---- I: MLP layer 2 (K=256) -> px ----
        {
            int i = tid & 255, rr = tid >> 8;
            float l2 = b2v;
            #pragma unroll 4
            for (int k4=0; k4<64; k4++){
                float4 w  = T2g[k4*256 + i];
                float4 xv = ((const float4*)s_l1[rr])[k4];
                l2 += xv.x*w.x + xv.y*w.y + xv.z*w.z + xv.w*w.w;
            }
            s_v[rr][i] = fmaxf(l2, 0.f);
        }
        __syncthreads();                                 // BAR8

        // ---- J: gates2 GEMV (K=512 over [px|h_post]) ----
        float a2[RPB];
        #pragma unroll
        for (int r=0;r<RPB;r++) a2[r] = brz;
        #pragma unroll 4
        for (int i4 = 0; i4 < 128; i4++){
            float4 w = Rg[i4*1024 + tid];
            #pragma unroll
            for (int r=0;r<RPB;r++){
                float4 xv = ((const float4*)s_v[r])[i4];
                a2[r] += xv.x*w.x + xv.y*w.y + xv.z*w.z + xv.w*w.w;
            }
        }
        __syncthreads();                                 // BAR9

        // ---- K: cell2 in registers; q==0 writes h_post ----
        #pragma unroll
        for (int r=0;r<RPB;r++){
            float pre = a2[r];
            float e  = __expf((q==2 ? -2.0f : -1.0f)*pre);
            float a_ = (q==2) ? (2.0f/(1.0f+e) - 1.0f) : (1.0f/(1.0f+e));
            float iv = __shfl(a_, b4+0);
            float fv = __shfl(a_, b4+1);
            float gv = __shfl(a_, b4+2);
            float ov = __shfl(a_, b4+3);
            float c  = fv*c2[r] + iv*gv;
            c2[r] = c;
            if (q == 0) s_v[r][256+u] = ov*tanhf_fast(c);
        }
        // no barrier: nothing before next J touches s_v's h region
    }
    __syncthreads();
    if (q == 0){
        #pragma unroll
        for (int r=0;r<RPB;r++){
            out[OUT_WC    + (r0+r)*256 + u] = c1[r];
            out[OUT_CPOST + (r0+r)*256 + u] = c2[r];
        }
    }
    if (tid < 256){
        #pragma unroll
        for (int r=0;r<RPB;r++){
            out[OUT_WH    + (r0+r)*256 + tid] = s_x[r][128+tid];
            out[OUT_HPOST + (r0+r)*256 + tid] = s_v[r][256+tid];
        }
    }
}

extern "C" void kernel_launch(void* const* d_in, const int* in_sizes, int n_in,
                              void* d_out, int out_size, void* d_ws, size_t ws_size,
                              hipStream_t stream) {
    const float* ext          = (const float*)d_in[0];
    const float* eps_init     = (const float*)d_in[1];
    const float* eps_seq      = (const float*)d_in[2];
    const float* eps_obs      = (const float*)d_in[3];
    const float* pp_W1        = (const float*)d_in[4];
    const float* pp_b1        = (const float*)d_in[5];
    const float* pp_W2        = (const float*)d_in[6];
    const float* pp_b2        = (const float*)d_in[7];
    const float* rnn_Wih      = (const float*)d_in[8];
    const float* rnn_Whh      = (const float*)d_in[9];
    const float* rnn_bih      = (const float*)d_in[10];
    const float* rnn_bhh      = (const float*)d_in[11];
    const float* posterior_h0 = (const float*)d_in[12];
    const float* gd_W1        = (const float*)d_in[13];
    const float* gd_b1        = (const float*)d_in[14];
    const float* gd_W2        = (const float*)d_in[15];
    const float* gd_b2        = (const float*)d_in[16];
    const float* gd_Wmu       = (const float*)d_in[17];
    const float* gd_bmu       = (const float*)d_in[18];
    const float* gd_Wls       = (const float*)d_in[19];
    const float* gd_bls       = (const float*)d_in[20];
    const float* dyn_h0       = (const float*)d_in[21];
    const float* wlstm_Wih    = (const float*)d_in[22];
    const float* wlstm_Whh    = (const float*)d_in[23];
    const float* wlstm_bih    = (const float*)d_in[24];
    const float* wlstm_bhh    = (const float*)d_in[25];
    const float* wl_W         = (const float*)d_in[26];
    const float* wl_b         = (const float*)d_in[27];
    const float* lin_W        = (const float*)d_in[28];
    const float* lin_b        = (const float*)d_in[29];
    const float* dyn_logsigma = (const float*)d_in[30];
    const float* est_logdelta = (const float*)d_in[31];
    const float* est_H        = (const float*)d_in[32];
    const float* est_bias     = (const float*)d_in[33];
    float* out = (float*)d_out;
    float* ws  = (float*)d_ws;

    prep_wcat<<<1536, 256, 0, stream>>>(wlstm_Wih, wlstm_Whh, ws);
    prep_lin <<<640,  256, 0, stream>>>(lin_W, ws);
    prep_rnn <<<2048, 256, 0, stream>>>(rnn_Wih, rnn_Whh, ws);
    prep_bias<<<4,    256, 0, stream>>>(wlstm_bih, wlstm_bhh, rnn_bih, rnn_bhh, lin_b, ws);
    prep_pp  <<<352,  256, 0, stream>>>(pp_W1, pp_W2, ws);
    dblock0  <<<1,    512, 0, stream>>>(posterior_h0, gd_W1, gd_b1, gd_W2, gd_b2,
                                        gd_Wmu, gd_bmu, gd_Wls, gd_bls, ws);
    scan_fused<<<256, 1024, 0, stream>>>(ext, eps_init, eps_seq, eps_obs,
                                         dyn_h0, posterior_h0,
                                         wl_W, wl_b, dyn_logsigma,
                                         est_logdelta, est_H, est_bias,
                                         pp_b1, pp_b2, ws, out);
}

// Round 3
// 18730.728 us; speedup vs baseline: 1.4279x; 1.4279x over previous
//
#include <hip/hip_runtime.h>

// ---- problem constants ----
#define RPB 4            // batch rows per block

// f16 vector type + dot2
typedef _Float16 h2 __attribute__((ext_vector_type(2)));
union F4H8 { float4 f; h2 h[4]; };
#if defined(__has_builtin)
#  if __has_builtin(__builtin_amdgcn_fdot2)
#    define FDOT2(a,b,c) __builtin_amdgcn_fdot2((a),(b),(c),false)
#  endif
#endif
#ifndef FDOT2
#  define FDOT2(a,b,c) ((c) + (float)(a).x*(float)(b).x + (float)(a).y*(float)(b).y)
#endif
__device__ __forceinline__ h2 pack2(float a, float b){ h2 r; r.x=(_Float16)a; r.y=(_Float16)b; return r; }

// ---- ws layout ----
// f16 region (offsets in HALF elements, all 16B-aligned)
#define WSH_WCAT  0                        // [48][1024][8]  gates1 W, col=u*4+q, k8-tiled
#define WSH_LINT  393216                   // [20][1024][8]  lin W, col=s*8+n
#define WSH_RNNT  557056                   // [64][1024][8]  gates2 W
#define WSH_PPT1  1081344                  // [12][256][8]
#define WSH_PPT2  1105920                  // [32][256][8]   (end 1171456 halves)
// f32 region (offsets in FLOAT elements)
#define WS_BZ     600000                   // [1024] combined wlstm bias, col=u*4+q
#define WS_LINB   601024                   // [1024] lin_b, col=s*8+n
#define WS_BRNN   602048                   // [1024]
#define WS_MU0    603072                   // [128]
#define WS_SEXP   603200                   // [128] exp(0.5*ls0)

// out offsets (return order, flat)
#define OUT_OBS_MU 0
#define OUT_OBS_S  (256*1024*64)
#define OUT_HPOST  (2*256*1024*64)
#define OUT_CPOST  (OUT_HPOST + 1024*256)
#define OUT_WH     (OUT_CPOST + 1024*256)
#define OUT_WC     (OUT_WH + 1024*256)
#define OUT_WMAP   (OUT_WC + 1024*256)

__device__ __forceinline__ float sigm(float x){ return 1.0f/(1.0f+__expf(-x)); }
__device__ __forceinline__ float tanhf_fast(float x){ return 2.0f/(1.0f+__expf(-2.0f*x)) - 1.0f; }

// ---------------- prep kernels: convert + retile weights to f16 ----------------
__global__ void prep_wcat(const float* __restrict__ Wih, const float* __restrict__ Whh,
                          _Float16* __restrict__ wsh){
    int idx = blockIdx.x*256 + threadIdx.x;          // < 48*8192
    int k8 = idx >> 13, rem = idx & 8191;
    int col = rem >> 3, j = rem & 7;
    int k = (k8 << 3) | j;
    int u = col >> 2, q = col & 3;                   // PyTorch gate order i,f,g,o
    float v = (k < 128) ? Wih[(q*256+u)*128 + k] : Whh[(q*256+u)*256 + (k-128)];
    wsh[WSH_WCAT + idx] = (_Float16)v;
}
__global__ void prep_lin(const float* __restrict__ lin_W, _Float16* __restrict__ wsh){
    int idx = blockIdx.x*256 + threadIdx.x;          // < 20*8192
    int k8 = idx >> 13, rem = idx & 8191;
    int col = rem >> 3, j = rem & 7;
    int k = (k8 << 3) | j;
    int s = col >> 3, n = col & 7;
    wsh[WSH_LINT + idx] = (_Float16)lin_W[(n*128 + s)*160 + k];
}
__global__ void prep_rnn(const float* __restrict__ Wih, const float* __restrict__ Whh,
                         _Float16* __restrict__ wsh){
    int idx = blockIdx.x*256 + threadIdx.x;          // < 64*8192
    int k8 = idx >> 13, rem = idx & 8191;
    int col = rem >> 3, j = rem & 7;
    int k = (k8 << 3) | j;
    int u = col >> 2, q = col & 3;
    float v = (k < 256) ? Wih[(q*256+u)*256 + k] : Whh[(q*256+u)*256 + (k-256)];
    wsh[WSH_RNNT + idx] = (_Float16)v;
}
__global__ void prep_pp(const float* __restrict__ W1, const float* __restrict__ W2,
                        _Float16* __restrict__ wsh){
    int idx = blockIdx.x*256 + threadIdx.x;          // < 12*2048 + 32*2048
    if (idx < 12*2048){
        int k8 = idx >> 11, rem = idx & 2047;
        int i = rem >> 3, j = rem & 7;
        wsh[WSH_PPT1 + idx] = (_Float16)W1[i*96 + (k8*8 + j)];
    } else {
        int kk = idx - 12*2048;
        int k8 = kk >> 11, rem = kk & 2047;
        int i = rem >> 3, j = rem & 7;
        wsh[WSH_PPT2 + kk] = (_Float16)W2[i*256 + (k8*8 + j)];
    }
}
__global__ void prep_bias(const float* __restrict__ wbih, const float* __restrict__ wbhh,
                          const float* __restrict__ rbih, const float* __restrict__ rbhh,
                          const float* __restrict__ lin_b, float* __restrict__ ws){
    int idx = blockIdx.x*256 + threadIdx.x;          // < 1024
    int u = idx >> 2, q = idx & 3;
    ws[WS_BZ + idx]   = wbih[q*256+u] + wbhh[q*256+u];
    ws[WS_BRNN + idx] = rbih[q*256+u] + rbhh[q*256+u];
    int s = idx >> 3, n = idx & 7;
    ws[WS_LINB + idx] = lin_b[n*128 + s];
}
// initial DBlock on the single broadcast h0 row (f32)
__global__ void dblock0(const float* __restrict__ h0,
                        const float* __restrict__ W1, const float* __restrict__ b1,
                        const float* __restrict__ W2, const float* __restrict__ b2,
                        const float* __restrict__ Wmu, const float* __restrict__ bmu,
                        const float* __restrict__ Wls, const float* __restrict__ bls,
                        float* __restrict__ ws){
    __shared__ float s_t[512];
    __shared__ float s_h[256];
    int tid = threadIdx.x;                            // 512 threads
    if (tid < 256) s_h[tid] = h0[tid];
    __syncthreads();
    {
        float a = b1[tid], b = b2[tid];
        for (int i=0;i<256;i++){ float h = s_h[i]; a += h*W1[tid*256+i]; b += h*W2[tid*256+i]; }
        s_t[tid] = tanhf_fast(a)*sigm(b);
    }
    __syncthreads();
    if (tid < 128){
        float m = bmu[tid];
        for (int k=0;k<512;k++) m += s_t[k]*Wmu[tid*512+k];
        ws[WS_MU0 + tid] = m;
    } else if (tid < 256){
        int j = tid - 128;
        float l = bls[j];
        for (int k=0;k<512;k++) l += s_t[k]*Wls[j*512+k];
        ws[WS_SEXP + j] = __expf(0.5f*l);
    }
}

// ---------------- fused scan, f16 weights/activations, f32 accumulate ----------------
__global__ __launch_bounds__(1024, 4) void scan_fused(
    const float* __restrict__ ext, const float* __restrict__ eps_init,
    const float* __restrict__ eps_seq, const float* __restrict__ eps_obs,
    const float* __restrict__ dyn_h0, const float* __restrict__ posterior_h0,
    const float* __restrict__ wl_W, const float* __restrict__ wl_b,
    const float* __restrict__ dyn_logsigma,
    const float* __restrict__ est_logdelta, const float* __restrict__ est_H,
    const float* __restrict__ est_b,
    const float* __restrict__ pp_b1, const float* __restrict__ pp_b2,
    const float* __restrict__ ws, float* __restrict__ out)
{
    const int tid  = threadIdx.x;
    const int lane = tid & 63;
    const int b4   = lane & ~3;          // base of 4-lane gate group
    const int r0   = blockIdx.x * RPB;
    const int u    = tid >> 2, q = tid & 3;   // gates column mapping col=u*4+q
    const _Float16* __restrict__ wsh = (const _Float16*)ws;

    __shared__ __align__(16) _Float16 s_x[RPB][384];   // [state(128) | h_w(256)]
    __shared__ __align__(16) _Float16 s_xc[RPB][160];  // [state(128) | u(t)(32)]
    __shared__ __align__(16) _Float16 s_v[RPB][512];   // [px(256) | h_post(256)]
    __shared__ __align__(16) _Float16 s_ax[RPB][96];   // [u(t)(32) | obs_s(t)(64)]
    __shared__ __align__(16) _Float16 s_l1[RPB][256];
    __shared__ float s_pe[4][RPB][64];                 // emission split-K partials
    __shared__ float s_wlog[RPB][8];
    __shared__ float s_dstd[128];
    __shared__ float s_ostd[64], s_eb[64];

    // --- loop-invariant register weights ---
    // emission: thread (o, kq) owns 32 H elements
    const int eo = tid & 63, err_ = (tid >> 6) & 3, ekq = tid >> 8;
    h2 ht[16];
    {
        const float* Hrow = est_H + eo*128 + ekq*32;
        #pragma unroll
        for (int m=0;m<16;m++) ht[m] = pack2(Hrow[2*m], Hrow[2*m+1]);
    }
    // wl logits: thread (n, part) owns 8 wl_W elements
    const int ln = (tid >> 5) & 7, lpart = tid & 31;
    h2 wl4[4]; float wlb;
    {
        const float* wr = wl_W + ln*256 + lpart*8;
        #pragma unroll
        for (int m=0;m<4;m++) wl4[m] = pack2(wr[2*m], wr[2*m+1]);
        wlb = wl_b[ln];
    }

    if (tid < 128) s_dstd[tid] = __expf(0.5f*dyn_logsigma[tid]);
    if (tid < 64){ s_ostd[tid] = __expf(0.5f*est_logdelta[tid]); s_eb[tid] = est_b[tid]; }
    if (tid < 128){
        float m = ws[WS_MU0+tid], sd = ws[WS_SEXP+tid];
        #pragma unroll
        for (int r=0;r<RPB;r++){
            float v = m + sd*eps_init[(r0+r)*128 + tid];
            s_x[r][tid] = (_Float16)v; s_xc[r][tid] = (_Float16)v;
        }
    }
    if (tid < 256){
        float h0v = dyn_h0[tid], hp = posterior_h0[tid];
        #pragma unroll
        for (int r=0;r<RPB;r++){ s_x[r][128+tid] = (_Float16)h0v; s_v[r][256+tid] = (_Float16)hp; }
    }
    if (tid < 64){                           // stage u(0) as f16 pairs
        int r = tid >> 4, ii = tid & 15;
        const float* e = ext + (r0+r)*32 + ii*2;
        *(h2*)&s_xc[r][128+ii*2] = pack2(e[0], e[1]);
    }
    float c1[RPB], c2[RPB];
    #pragma unroll
    for (int r=0;r<RPB;r++){ c1[r] = 0.0f; c2[r] = 0.0f; }

    const float bz  = ws[WS_BZ + tid];
    const float lb  = ws[WS_LINB + tid];
    const float brz = ws[WS_BRNN + tid];
    const float b1v = pp_b1[tid & 255];
    const float b2v = pp_b2[tid & 255];
    const float4* __restrict__ Wg4  = (const float4*)(wsh + WSH_WCAT);
    const float4* __restrict__ Lg4  = (const float4*)(wsh + WSH_LINT);
    const float4* __restrict__ Rg4  = (const float4*)(wsh + WSH_RNNT);
    const float4* __restrict__ T1g4 = (const float4*)(wsh + WSH_PPT1);
    const float4* __restrict__ T2g4 = (const float4*)(wsh + WSH_PPT2);
    __syncthreads();

    for (int t = 0; t < 256; t++){
        // ---- A: gates1 GEMV (K=384) + mus GEMV (K=160) via dot2 ----
        float ac[RPB], am[RPB];
        #pragma unroll
        for (int r=0;r<RPB;r++){ ac[r] = bz; am[r] = lb; }
        #pragma unroll 2
        for (int i8 = 0; i8 < 48; i8++){
            F4H8 w; w.f = Wg4[i8*1024 + tid];
            #pragma unroll
            for (int r=0;r<RPB;r++){
                F4H8 x; x.f = ((const float4*)s_x[r])[i8];
                ac[r] = FDOT2(w.h[0], x.h[0], ac[r]);
                ac[r] = FDOT2(w.h[1], x.h[1], ac[r]);
                ac[r] = FDOT2(w.h[2], x.h[2], ac[r]);
                ac[r] = FDOT2(w.h[3], x.h[3], ac[r]);
            }
        }
        #pragma unroll 2
        for (int i8 = 0; i8 < 20; i8++){
            F4H8 w; w.f = Lg4[i8*1024 + tid];
            #pragma unroll
            for (int r=0;r<RPB;r++){
                F4H8 x; x.f = ((const float4*)s_xc[r])[i8];
                am[r] = FDOT2(w.h[0], x.h[0], am[r]);
                am[r] = FDOT2(w.h[1], x.h[1], am[r]);
                am[r] = FDOT2(w.h[2], x.h[2], am[r]);
                am[r] = FDOT2(w.h[3], x.h[3], am[r]);
            }
        }
        __syncthreads();                                 // BAR1

        // ---- B: cell1 in registers (4-lane shuffle); q==0 writes h ----
        #pragma unroll
        for (int r=0;r<RPB;r++){
            float pre = ac[r];
            float e  = __expf((q==2 ? -2.0f : -1.0f)*pre);
            float a_ = (q==2) ? (2.0f/(1.0f+e) - 1.0f) : (1.0f/(1.0f+e));
            float iv = __shfl(a_, b4+0);
            float fv = __shfl(a_, b4+1);
            float gv = __shfl(a_, b4+2);
            float ov = __shfl(a_, b4+3);
            float c  = fv*c1[r] + iv*gv;
            c1[r] = c;
            if (q == 0) s_x[r][128+u] = (_Float16)(ov*tanhf_fast(c));
        }
        if (tid < 64){                        // copy u(t) into s_ax for the MLP
            int r = tid >> 4, ii = tid & 15;
            *(h2*)&s_ax[r][ii*2] = *(const h2*)&s_xc[r][128+ii*2];
        }
        __syncthreads();                                 // BAR2

        // ---- C: wl logits, register weights, split-K over 32 lanes ----
        {
            int rr = tid >> 8;
            const h2* hrow = (const h2*)&s_x[rr][128 + lpart*8];
            float p = 0.f;
            p = FDOT2(wl4[0], hrow[0], p);
            p = FDOT2(wl4[1], hrow[1], p);
            p = FDOT2(wl4[2], hrow[2], p);
            p = FDOT2(wl4[3], hrow[3], p);
            p += __shfl_xor(p, 1);
            p += __shfl_xor(p, 2);
            p += __shfl_xor(p, 4);
            p += __shfl_xor(p, 8);
            p += __shfl_xor(p, 16);
            if (lpart == 0) s_wlog[rr][ln] = p + wlb;
        }
        __syncthreads();                                 // BAR3

        // ---- E: softmax in 8-lane group + weighted combine + resample ----
        {
            int s = tid >> 3, n = tid & 7;
            #pragma unroll
            for (int r=0;r<RPB;r++){
                float lg = s_wlog[r][n];
                float mx = lg;
                mx = fmaxf(mx, __shfl_xor(mx, 1));
                mx = fmaxf(mx, __shfl_xor(mx, 2));
                mx = fmaxf(mx, __shfl_xor(mx, 4));
                float e = __expf(lg - mx);
                float sm = e;
                sm += __shfl_xor(sm, 1);
                sm += __shfl_xor(sm, 2);
                sm += __shfl_xor(sm, 4);
                float w = __fdividef(e, sm);
                if (s == 0)                               // tid<8: wmap out
                    out[OUT_WMAP + (t*1024 + r0 + r)*8 + n] = w;
                float p = am[r]*w;
                p += __shfl_xor(p, 1);
                p += __shfl_xor(p, 2);
                p += __shfl_xor(p, 4);
                if (n == 0){
                    float st = p + s_dstd[s]*eps_seq[(t*1024 + r0 + r)*128 + s];
                    s_x[r][s] = (_Float16)st; s_xc[r][s] = (_Float16)st;
                }
            }
            if (t < 255 && tid < 64){                     // stage u(t+1)
                int r = tid >> 4, ii = tid & 15;
                const float* e = ext + ((t+1)*1024 + r0 + r)*32 + ii*2;
                *(h2*)&s_xc[r][128+ii*2] = pack2(e[0], e[1]);
            }
        }
        __syncthreads();                                 // BAR4

        // ---- F: emission partials (split-K=4), H in registers ----
        {
            const h2* xr = (const h2*)&s_x[err_][ekq*32];
            float a = 0.f;
            #pragma unroll
            for (int m=0;m<16;m++) a = FDOT2(ht[m], xr[m], a);
            s_pe[ekq][err_][eo] = a;
        }
        __syncthreads();                                 // BAR5

        // ---- G: emission reduce; obs to out AND into s_ax ----
        if (tid < 256){
            int o = tid & 63, rr = tid >> 6;
            float a = s_eb[o] + s_pe[0][rr][o] + s_pe[1][rr][o]
                    + s_pe[2][rr][o] + s_pe[3][rr][o];
            int base = (t*1024 + r0 + rr)*64 + o;
            out[OUT_OBS_MU + base] = a;
            float os = a + s_ostd[o]*eps_obs[base];
            out[OUT_OBS_S + base] = os;
            s_ax[rr][32+o] = (_Float16)os;
        }
        __syncthreads();                                 // BAR6

        // ---- H: MLP layer 1 (thread = (i, rr), K=96) ----
        {
            int i = tid & 255, rr = tid >> 8;
            float l1 = b1v;
            #pragma unroll
            for (int i8=0; i8<12; i8++){
                F4H8 w; w.f = T1g4[i8*256 + i];
                F4H8 x; x.f = ((const float4*)s_ax[rr])[i8];
                l1 = FDOT2(w.h[0], x.h[0], l1);
                l1 = FDOT2(w.h[1], x.h[1], l1);
                l1 = FDOT2(w.h[2], x.h[2], l1);
                l1 = FDOT2(w.h[3], x.h[3], l1);
            }
            s_l1[rr][i] = (_Float16)fmaxf(l1, 0.f);
        }
        __syncthreads();                                 // BAR7

        // ---- I: MLP layer 2 (K=256) -> px ----
        {
            int i = tid & 255, rr = tid >> 8;
            float l2 = b2v;
            #pragma unroll 4
            for (int i8=0; i8<32; i8++){
                F4H8 w; w.f = T2g4[i8*256 + i];
                F4H8 x; x.f = ((const float4*)s_l1[rr])[i8];
                l2 = FDOT2(w.h[0], x.h[0], l2);
                l2 = FDOT2(w.h[1], x.h[1], l2);
                l2 = FDOT2(w.h[2], x.h[2], l2);
                l2 = FDOT2(w.h[3], x.h[3], l2);
            }
            s_v[rr][i] = (_Float16)fmaxf(l2, 0.f);
        }
        __syncthreads();                                 // BAR8

        // ---- J: gates2 GEMV (K=512 over [px|h_post]) ----
        float a2[RPB];
        #pragma unroll
        for (int r=0;r<RPB;r++) a2[r] = brz;
        #pragma unroll 2
        for (int i8 = 0; i8 < 64; i8++){
            F4H8 w; w.f = Rg4[i8*1024 + tid];
            #pragma unroll
            for (int r=0;r<RPB;r++){
                F4H8 x; x.f = ((const float4*)s_v[r])[i8];
                a2[r] = FDOT2(w.h[0], x.h[0], a2[r]);
                a2[r] = FDOT2(w.h[1], x.h[1], a2[r]);
                a2[r] = FDOT2(w.h[2], x.h[2], a2[r]);
                a2[r] = FDOT2(w.h[3], x.h[3], a2[r]);
            }
        }
        __syncthreads();                                 // BAR9

        // ---- K: cell2 in registers; q==0 writes h_post ----
        #pragma unroll
        for (int r=0;r<RPB;r++){
            float pre = a2[r];
            float e  = __expf((q==2 ? -2.0f : -1.0f)*pre);
            float a_ = (q==2) ? (2.0f/(1.0f+e) - 1.0f) : (1.0f/(1.0f+e));
            float iv = __shfl(a_, b4+0);
            float fv = __shfl(a_, b4+1);
            float gv = __shfl(a_, b4+2);
            float ov = __shfl(a_, b4+3);
            float c  = fv*c2[r] + iv*gv;
            c2[r] = c;
            if (q == 0) s_v[r][256+u] = (_Float16)(ov*tanhf_fast(c));
        }
        // no barrier: next access to s_v's h region is J, many barriers away
    }
    __syncthreads();
    if (q == 0){
        #pragma unroll
        for (int r=0;r<RPB;r++){
            out[OUT_WC    + (r0+r)*256 + u] = c1[r];
            out[OUT_CPOST + (r0+r)*256 + u] = c2[r];
        }
    }
    if (tid < 256){
        #pragma unroll
        for (int r=0;r<RPB;r++){
            out[OUT_WH    + (r0+r)*256 + tid] = (float)s_x[r][128+tid];
            out[OUT_HPOST + (r0+r)*256 + tid] = (float)s_v[r][256+tid];
        }
    }
}

extern "C" void kernel_launch(void* const* d_in, const int* in_sizes, int n_in,
                              void* d_out, int out_size, void* d_ws, size_t ws_size,
                              hipStream_t stream) {
    const float* ext          = (const float*)d_in[0];
    const float* eps_init     = (const float*)d_in[1];
    const float* eps_seq      = (const float*)d_in[2];
    const float* eps_obs      = (const float*)d_in[3];
    const float* pp_W1        = (const float*)d_in[4];
    const float* pp_b1        = (const float*)d_in[5];
    const float* pp_W2        = (const float*)d_in[6];
    const float* pp_b2        = (const float*)d_in[7];
    const float* rnn_Wih      = (const float*)d_in[8];
    const float* rnn_Whh      = (const float*)d_in[9];
    const float* rnn_bih      = (const float*)d_in[10];
    const float* rnn_bhh      = (const float*)d_in[11];
    const float* posterior_h0 = (const float*)d_in[12];
    const float* gd_W1        = (const float*)d_in[13];
    const float* gd_b1        = (const float*)d_in[14];
    const float* gd_W2        = (const float*)d_in[15];
    const float* gd_b2        = (const float*)d_in[16];
    const float* gd_Wmu       = (const float*)d_in[17];
    const float* gd_bmu       = (const float*)d_in[18];
    const float* gd_Wls       = (const float*)d_in[19];
    const float* gd_bls       = (const float*)d_in[20];
    const float* dyn_h0       = (const float*)d_in[21];
    const float* wlstm_Wih    = (const float*)d_in[22];
    const float* wlstm_Whh    = (const float*)d_in[23];
    const float* wlstm_bih    = (const float*)d_in[24];
    const float* wlstm_bhh    = (const float*)d_in[25];
    const float* wl_W         = (const float*)d_in[26];
    const float* wl_b         = (const float*)d_in[27];
    const float* lin_W        = (const float*)d_in[28];
    const float* lin_b        = (const float*)d_in[29];
    const float* dyn_logsigma = (const float*)d_in[30];
    const float* est_logdelta = (const float*)d_in[31];
    const float* est_H        = (const float*)d_in[32];
    const float* est_bias     = (const float*)d_in[33];
    float* out = (float*)d_out;
    float* ws  = (float*)d_ws;
    _Float16* wsh = (_Float16*)d_ws;

    prep_wcat<<<1536, 256, 0, stream>>>(wlstm_Wih, wlstm_Whh, wsh);
    prep_lin <<<640,  256, 0, stream>>>(lin_W, wsh);
    prep_rnn <<<2048, 256, 0, stream>>>(rnn_Wih, rnn_Whh, wsh);
    prep_pp  <<<352,  256, 0, stream>>>(pp_W1, pp_W2, wsh);
    prep_bias<<<4,    256, 0, stream>>>(wlstm_bih, wlstm_bhh, rnn_bih, rnn_bhh, lin_b, ws);
    dblock0  <<<1,    512, 0, stream>>>(posterior_h0, gd_W1, gd_b1, gd_W2, gd_b2,
                                        gd_Wmu, gd_bmu, gd_Wls, gd_bls, ws);
    scan_fused<<<256, 1024, 0, stream>>>(ext, eps_init, eps_seq, eps_obs,
                                         dyn_h0, posterior_h0,
                                         wl_W, wl_b, dyn_logsigma,
                                         est_logdelta, est_H, est_bias,
                                         pp_b1, pp_b2, ws, out);
}

// Round 4
// 13895.551 us; speedup vs baseline: 1.9247x; 1.3480x over previous
//
#include <hip/hip_runtime.h>

// ---- problem constants ----
#define RPB 4            // batch rows per block

// f16 vector type + dot2
typedef _Float16 h2 __attribute__((ext_vector_type(2)));
union F4H8 { float4 f; h2 h[4]; };
#if defined(__has_builtin)
#  if __has_builtin(__builtin_amdgcn_fdot2)
#    define FDOT2(a,b,c) __builtin_amdgcn_fdot2((a),(b),(c),false)
#  endif
#endif
#ifndef FDOT2
#  define FDOT2(a,b,c) ((c) + (float)(a).x*(float)(b).x + (float)(a).y*(float)(b).y)
#endif
__device__ __forceinline__ h2 pack2(float a, float b){ h2 r; r.x=(_Float16)a; r.y=(_Float16)b; return r; }

// ---- ws layout ----
// f16 region (offsets in HALF elements, all 16B-aligned)
// weight tiles: [k8][c][cg][kh][8h], k = k8*32 + kh*8 + j, col = cg*4 + c
#define WSH_WCAT  0                        // gates1 W: 12*4*256*4*8
#define WSH_LINT  393216                   // lin W:    5*4*256*4*8
#define WSH_RNNT  557056                   // gates2 W: 16*4*256*4*8
#define WSH_PPT1  1081344                  // [12][256][8]
#define WSH_PPT2  1105920                  // [32][256][8]
// f32 region (offsets in FLOAT elements)
#define WS_BZ     600000                   // [1024] combined wlstm bias, col=u*4+q
#define WS_LINB   601024                   // [1024] lin_b, col=s*8+n
#define WS_BRNN   602048                   // [1024]
#define WS_MU0    603072                   // [128]
#define WS_SEXP   603200                   // [128] exp(0.5*ls0)

// out offsets (return order, flat)
#define OUT_OBS_MU 0
#define OUT_OBS_S  (256*1024*64)
#define OUT_HPOST  (2*256*1024*64)
#define OUT_CPOST  (OUT_HPOST + 1024*256)
#define OUT_WH     (OUT_CPOST + 1024*256)
#define OUT_WC     (OUT_WH + 1024*256)
#define OUT_WMAP   (OUT_WC + 1024*256)

__device__ __forceinline__ float sigm(float x){ return 1.0f/(1.0f+__expf(-x)); }
__device__ __forceinline__ float tanhf_fast(float x){ return 2.0f/(1.0f+__expf(-2.0f*x)) - 1.0f; }
// static-index 4-way select (avoids runtime-indexed register arrays -> scratch)
__device__ __forceinline__ float sel4(float v0,float v1,float v2,float v3,int k){
    float r = v0; r = (k==1)?v1:r; r = (k==2)?v2:r; r = (k==3)?v3:r; return r;
}

// ---------------- prep kernels: convert + retile weights to f16 ----------------
// layout [k8][c][cg][kh][j]: idx bits j=idx&7, kh=(idx>>3)&3, cg=(idx>>5)&255,
// c=(idx>>13)&3, k8=idx>>15; source k = k8*32 + kh*8 + j
__global__ void prep_wcat(const float* __restrict__ Wih, const float* __restrict__ Whh,
                          _Float16* __restrict__ wsh){
    int idx = blockIdx.x*256 + threadIdx.x;          // < 12*32768
    int j = idx & 7, kh = (idx>>3)&3, cg = (idx>>5)&255, c = (idx>>13)&3, k8 = idx>>15;
    int k = k8*32 + kh*8 + j;
    int u = cg, q = c;                               // PyTorch gate order i,f,g,o
    float v = (k < 128) ? Wih[(q*256+u)*128 + k] : Whh[(q*256+u)*256 + (k-128)];
    wsh[WSH_WCAT + idx] = (_Float16)v;
}
__global__ void prep_lin(const float* __restrict__ lin_W, _Float16* __restrict__ wsh){
    int idx = blockIdx.x*256 + threadIdx.x;          // < 5*32768
    int j = idx & 7, kh = (idx>>3)&3, cg = (idx>>5)&255, c = (idx>>13)&3, k8 = idx>>15;
    int k = k8*32 + kh*8 + j;
    int col = cg*4 + c, s = col >> 3, n = col & 7;
    wsh[WSH_LINT + idx] = (_Float16)lin_W[(n*128 + s)*160 + k];
}
__global__ void prep_rnn(const float* __restrict__ Wih, const float* __restrict__ Whh,
                         _Float16* __restrict__ wsh){
    int idx = blockIdx.x*256 + threadIdx.x;          // < 16*32768
    int j = idx & 7, kh = (idx>>3)&3, cg = (idx>>5)&255, c = (idx>>13)&3, k8 = idx>>15;
    int k = k8*32 + kh*8 + j;
    int u = cg, q = c;
    float v = (k < 256) ? Wih[(q*256+u)*256 + k] : Whh[(q*256+u)*256 + (k-256)];
    wsh[WSH_RNNT + idx] = (_Float16)v;
}
__global__ void prep_pp(const float* __restrict__ W1, const float* __restrict__ W2,
                        _Float16* __restrict__ wsh){
    int idx = blockIdx.x*256 + threadIdx.x;          // < 12*2048 + 32*2048
    if (idx < 12*2048){
        int k8 = idx >> 11, rem = idx & 2047;
        int i = rem >> 3, j = rem & 7;
        wsh[WSH_PPT1 + idx] = (_Float16)W1[i*96 + (k8*8 + j)];
    } else {
        int kk = idx - 12*2048;
        int k8 = kk >> 11, rem = kk & 2047;
        int i = rem >> 3, j = rem & 7;
        wsh[WSH_PPT2 + kk] = (_Float16)W2[i*256 + (k8*8 + j)];
    }
}
__global__ void prep_bias(const float* __restrict__ wbih, const float* __restrict__ wbhh,
                          const float* __restrict__ rbih, const float* __restrict__ rbhh,
                          const float* __restrict__ lin_b, float* __restrict__ ws){
    int idx = blockIdx.x*256 + threadIdx.x;          // < 1024
    int u = idx >> 2, q = idx & 3;
    ws[WS_BZ + idx]   = wbih[q*256+u] + wbhh[q*256+u];
    ws[WS_BRNN + idx] = rbih[q*256+u] + rbhh[q*256+u];
    int s = idx >> 3, n = idx & 7;
    ws[WS_LINB + idx] = lin_b[n*128 + s];
}
// initial DBlock on the single broadcast h0 row (f32)
__global__ void dblock0(const float* __restrict__ h0,
                        const float* __restrict__ W1, const float* __restrict__ b1,
                        const float* __restrict__ W2, const float* __restrict__ b2,
                        const float* __restrict__ Wmu, const float* __restrict__ bmu,
                        const float* __restrict__ Wls, const float* __restrict__ bls,
                        float* __restrict__ ws){
    __shared__ float s_t[512];
    __shared__ float s_h[256];
    int tid = threadIdx.x;                            // 512 threads
    if (tid < 256) s_h[tid] = h0[tid];
    __syncthreads();
    {
        float a = b1[tid], b = b2[tid];
        for (int i=0;i<256;i++){ float h = s_h[i]; a += h*W1[tid*256+i]; b += h*W2[tid*256+i]; }
        s_t[tid] = tanhf_fast(a)*sigm(b);
    }
    __syncthreads();
    if (tid < 128){
        float m = bmu[tid];
        for (int k=0;k<512;k++) m += s_t[k]*Wmu[tid*512+k];
        ws[WS_MU0 + tid] = m;
    } else if (tid < 256){
        int j = tid - 128;
        float l = bls[j];
        for (int k=0;k<512;k++) l += s_t[k]*Wls[j*512+k];
        ws[WS_SEXP + j] = __expf(0.5f*l);
    }
}

// ---------------- fused scan: lane-split-K GEMVs, shfl_xor reduction ----------------
// thread t: kh = t&3 (K-quarter), cg = t>>2 (4 output cols 4cg..4cg+3).
// After shfl_xor(1),(2) each lane holds all 4 cols' full dots for 4 rows; it
// keeps row r==kh -> the whole LSTM cell for unit cg, row kh runs in-thread.
__global__ __launch_bounds__(1024, 4) void scan_fused(
    const float* __restrict__ ext, const float* __restrict__ eps_init,
    const float* __restrict__ eps_seq, const float* __restrict__ eps_obs,
    const float* __restrict__ dyn_h0, const float* __restrict__ posterior_h0,
    const float* __restrict__ wl_W, const float* __restrict__ wl_b,
    const float* __restrict__ dyn_logsigma,
    const float* __restrict__ est_logdelta, const float* __restrict__ est_H,
    const float* __restrict__ est_b,
    const float* __restrict__ pp_b1, const float* __restrict__ pp_b2,
    const float* __restrict__ ws, float* __restrict__ out)
{
    const int tid = threadIdx.x;
    const int kh  = tid & 3;       // K-quarter (lane bits 0-1)
    const int cg  = tid >> 2;      // column group
    const int r0  = blockIdx.x * RPB;
    const _Float16* __restrict__ wsh = (const _Float16*)ws;

    __shared__ __align__(16) _Float16 s_x[RPB][384];   // [state(128) | h_w(256)]
    __shared__ __align__(16) _Float16 s_xc[RPB][160];  // [state(128) | u(t)(32)]
    __shared__ __align__(16) _Float16 s_v[RPB][512];   // [px(256) | h_post(256)]
    __shared__ __align__(16) _Float16 s_ax[RPB][96];   // [u(t)(32) | obs_s(t)(64)]
    __shared__ __align__(16) _Float16 s_l1[RPB][256];
    __shared__ __align__(16) float s_pe[4][RPB][64];   // emission split-K partials
    __shared__ __align__(16) float s_wlog[RPB][8];
    __shared__ float s_dstd[128];
    __shared__ float s_ostd[64], s_eb[64];

    // --- loop-invariant register weights ---
    // emission: thread (o, kq) owns 32 H elements
    const int eo = tid & 63, err_ = (tid >> 6) & 3, ekq = tid >> 8;
    h2 ht[16];
    {
        const float* Hrow = est_H + eo*128 + ekq*32;
        #pragma unroll
        for (int m=0;m<16;m++) ht[m] = pack2(Hrow[2*m], Hrow[2*m+1]);
    }
    // wl logits: thread (n, part) owns 8 wl_W elements
    const int ln = (tid >> 5) & 7, lpart = tid & 31;
    h2 wl4[4]; float wlb;
    {
        const float* wr = wl_W + ln*256 + lpart*8;
        #pragma unroll
        for (int m=0;m<4;m++) wl4[m] = pack2(wr[2*m], wr[2*m+1]);
        wlb = wl_b[ln];
    }

    if (tid < 128) s_dstd[tid] = __expf(0.5f*dyn_logsigma[tid]);
    if (tid < 64){ s_ostd[tid] = __expf(0.5f*est_logdelta[tid]); s_eb[tid] = est_b[tid]; }
    if (tid < 128){
        float m = ws[WS_MU0+tid], sd = ws[WS_SEXP+tid];
        #pragma unroll
        for (int r=0;r<RPB;r++){
            float v = m + sd*eps_init[(r0+r)*128 + tid];
            s_x[r][tid] = (_Float16)v; s_xc[r][tid] = (_Float16)v;
        }
    }
    if (tid < 256){
        float h0v = dyn_h0[tid], hp = posterior_h0[tid];
        #pragma unroll
        for (int r=0;r<RPB;r++){ s_x[r][128+tid] = (_Float16)h0v; s_v[r][256+tid] = (_Float16)hp; }
    }
    if (tid < 64){                           // stage u(0) as f16 pairs
        int r = tid >> 4, ii = tid & 15;
        const float* e = ext + (r0+r)*32 + ii*2;
        *(h2*)&s_xc[r][128+ii*2] = pack2(e[0], e[1]);
    }
    float c1 = 0.0f, c2 = 0.0f;

    const float4 bz4 = ((const float4*)(ws + WS_BZ))[cg];
    const float4 lb4 = ((const float4*)(ws + WS_LINB))[cg];
    const float4 br4 = ((const float4*)(ws + WS_BRNN))[cg];
    const float b1v = pp_b1[tid & 255];
    const float b2v = pp_b2[tid & 255];
    const float4* __restrict__ Wg4  = (const float4*)(wsh + WSH_WCAT);
    const float4* __restrict__ Lg4  = (const float4*)(wsh + WSH_LINT);
    const float4* __restrict__ Rg4  = (const float4*)(wsh + WSH_RNNT);
    const float4* __restrict__ T1g4 = (const float4*)(wsh + WSH_PPT1);
    const float4* __restrict__ T2g4 = (const float4*)(wsh + WSH_PPT2);
    const int xsk = kh*8;                    // half-offset of this lane's b128 granule
    __syncthreads();

    for (int t = 0; t < 256; t++){
        // ---- A: gates1 (K=384) + mus (K=160), lane-split-K + shfl reduce ----
        float zi, zf, zg, zo;
        {
            float ga[4][4];                  // [c][r], all statically indexed
            #pragma unroll
            for (int c=0;c<4;c++){
                #pragma unroll
                for (int r=0;r<4;r++) ga[c][r] = 0.f;
            }
            #pragma unroll 2
            for (int k8=0;k8<12;k8++){
                F4H8 w0,w1,w2,w3;
                w0.f = Wg4[(k8*4+0)*1024 + tid];
                w1.f = Wg4[(k8*4+1)*1024 + tid];
                w2.f = Wg4[(k8*4+2)*1024 + tid];
                w3.f = Wg4[(k8*4+3)*1024 + tid];
                #pragma unroll
                for (int r=0;r<4;r++){
                    F4H8 x; x.f = *(const float4*)&s_x[r][k8*32 + xsk];
                    #pragma unroll
                    for (int p=0;p<4;p++){
                        ga[0][r] = FDOT2(w0.h[p], x.h[p], ga[0][r]);
                        ga[1][r] = FDOT2(w1.h[p], x.h[p], ga[1][r]);
                        ga[2][r] = FDOT2(w2.h[p], x.h[p], ga[2][r]);
                        ga[3][r] = FDOT2(w3.h[p], x.h[p], ga[3][r]);
                    }
                }
            }
            #pragma unroll
            for (int c=0;c<4;c++){
                #pragma unroll
                for (int r=0;r<4;r++){
                    ga[c][r] += __shfl_xor(ga[c][r], 1);
                    ga[c][r] += __shfl_xor(ga[c][r], 2);
                }
            }
            zi = sel4(ga[0][0],ga[0][1],ga[0][2],ga[0][3],kh) + bz4.x;
            zf = sel4(ga[1][0],ga[1][1],ga[1][2],ga[1][3],kh) + bz4.y;
            zg = sel4(ga[2][0],ga[2][1],ga[2][2],ga[2][3],kh) + bz4.z;
            zo = sel4(ga[3][0],ga[3][1],ga[3][2],ga[3][3],kh) + bz4.w;
        }
        float mu0, mu1, mu2, mu3;
        {
            float ma[4][4];
            #pragma unroll
            for (int c=0;c<4;c++){
                #pragma unroll
                for (int r=0;r<4;r++) ma[c][r] = 0.f;
            }
            #pragma unroll
            for (int k8=0;k8<5;k8++){
                F4H8 w0,w1,w2,w3;
                w0.f = Lg4[(k8*4+0)*1024 + tid];
                w1.f = Lg4[(k8*4+1)*1024 + tid];
                w2.f = Lg4[(k8*4+2)*1024 + tid];
                w3.f = Lg4[(k8*4+3)*1024 + tid];
                #pragma unroll
                for (int r=0;r<4;r++){
                    F4H8 x; x.f = *(const float4*)&s_xc[r][k8*32 + xsk];
                    #pragma unroll
                    for (int p=0;p<4;p++){
                        ma[0][r] = FDOT2(w0.h[p], x.h[p], ma[0][r]);
                        ma[1][r] = FDOT2(w1.h[p], x.h[p], ma[1][r]);
                        ma[2][r] = FDOT2(w2.h[p], x.h[p], ma[2][r]);
                        ma[3][r] = FDOT2(w3.h[p], x.h[p], ma[3][r]);
                    }
                }
            }
            #pragma unroll
            for (int c=0;c<4;c++){
                #pragma unroll
                for (int r=0;r<4;r++){
                    ma[c][r] += __shfl_xor(ma[c][r], 1);
                    ma[c][r] += __shfl_xor(ma[c][r], 2);
                }
            }
            mu0 = sel4(ma[0][0],ma[0][1],ma[0][2],ma[0][3],kh) + lb4.x;
            mu1 = sel4(ma[1][0],ma[1][1],ma[1][2],ma[1][3],kh) + lb4.y;
            mu2 = sel4(ma[2][0],ma[2][1],ma[2][2],ma[2][3],kh) + lb4.z;
            mu3 = sel4(ma[3][0],ma[3][1],ma[3][2],ma[3][3],kh) + lb4.w;
        }
        __syncthreads();                                 // BAR1

        // ---- B: cell1 for (u=cg, row=kh); u(t)->s_ax; stage u(t+1) ----
        {
            float ig = sigm(zi), fg = sigm(zf);
            float gg = tanhf_fast(zg), og = sigm(zo);
            c1 = fg*c1 + ig*gg;
            s_x[kh][128+cg] = (_Float16)(og*tanhf_fast(c1));
        }
        if (tid < 64){
            int r = tid >> 4, ii = tid & 15;
            *(h2*)&s_ax[r][ii*2] = *(const h2*)&s_xc[r][128+ii*2];
            if (t < 255){
                const float* e = ext + ((t+1)*1024 + r0 + r)*32 + ii*2;
                *(h2*)&s_xc[r][128+ii*2] = pack2(e[0], e[1]);
            }
        }
        __syncthreads();                                 // BAR2

        // ---- C: wl logits, register weights, split-K over 32 lanes ----
        {
            int rr = tid >> 8;
            const h2* hrow = (const h2*)&s_x[rr][128 + lpart*8];
            float p = 0.f;
            p = FDOT2(wl4[0], hrow[0], p);
            p = FDOT2(wl4[1], hrow[1], p);
            p = FDOT2(wl4[2], hrow[2], p);
            p = FDOT2(wl4[3], hrow[3], p);
            p += __shfl_xor(p, 1);
            p += __shfl_xor(p, 2);
            p += __shfl_xor(p, 4);
            p += __shfl_xor(p, 8);
            p += __shfl_xor(p, 16);
            if (lpart == 0) s_wlog[rr][ln] = p + wlb;
        }
        __syncthreads();                                 // BAR3

        // ---- E: in-thread softmax (row kh) + combine + resample ----
        {
            float4 lg0 = *(const float4*)&s_wlog[kh][0];
            float4 lg1 = *(const float4*)&s_wlog[kh][4];
            float mx = fmaxf(fmaxf(fmaxf(lg0.x,lg0.y),fmaxf(lg0.z,lg0.w)),
                             fmaxf(fmaxf(lg1.x,lg1.y),fmaxf(lg1.z,lg1.w)));
            float e0=__expf(lg0.x-mx), e1=__expf(lg0.y-mx), e2=__expf(lg0.z-mx), e3=__expf(lg0.w-mx);
            float e4=__expf(lg1.x-mx), e5=__expf(lg1.y-mx), e6=__expf(lg1.z-mx), e7=__expf(lg1.w-mx);
            float inv = 1.0f/(e0+e1+e2+e3+e4+e5+e6+e7);
            int hi = cg & 1;
            float w0 = (hi? e4:e0)*inv;
            float w1 = (hi? e5:e1)*inv;
            float w2 = (hi? e6:e2)*inv;
            float w3 = (hi? e7:e3)*inv;
            float p = mu0*w0 + mu1*w1 + mu2*w2 + mu3*w3;
            p += __shfl_xor(p, 4);                       // sum the two n-halves
            if (!hi){
                int s = cg >> 1;
                float st = p + s_dstd[s]*eps_seq[(t*1024 + r0 + kh)*128 + s];
                s_x[kh][s] = (_Float16)st; s_xc[kh][s] = (_Float16)st;
            }
            if (cg < 2){
                float* wm = out + OUT_WMAP + (t*1024 + r0 + kh)*8 + hi*4;
                wm[0]=w0; wm[1]=w1; wm[2]=w2; wm[3]=w3;
            }
        }
        __syncthreads();                                 // BAR4

        // ---- F: emission partials (split-K=4), H in registers ----
        {
            const h2* xr = (const h2*)&s_x[err_][ekq*32];
            float a = 0.f;
            #pragma unroll
            for (int m=0;m<16;m++) a = FDOT2(ht[m], xr[m], a);
            s_pe[ekq][err_][eo] = a;
        }
        __syncthreads();                                 // BAR5

        // ---- G: emission reduce; obs to out AND into s_ax ----
        if (tid < 256){
            int o = tid & 63, rr = tid >> 6;
            float a = s_eb[o] + s_pe[0][rr][o] + s_pe[1][rr][o]
                    + s_pe[2][rr][o] + s_pe[3][rr][o];
            int base = (t*1024 + r0 + rr)*64 + o;
            out[OUT_OBS_MU + base] = a;
            float os = a + s_ostd[o]*eps_obs[base];
            out[OUT_OBS_S + base] = os;
            s_ax[rr][32+o] = (_Float16)os;
        }
        __syncthreads();                                 // BAR6

        // ---- H: MLP layer 1 (thread = (i, rr), K=96) ----
        {
            int i = tid & 255, rr = tid >> 8;
            float l1 = b1v;
            #pragma unroll
            for (int i8=0; i8<12; i8++){
                F4H8 w; w.f = T1g4[i8*256 + i];
                F4H8 x; x.f = ((const float4*)s_ax[rr])[i8];
                l1 = FDOT2(w.h[0], x.h[0], l1);
                l1 = FDOT2(w.h[1], x.h[1], l1);
                l1 = FDOT2(w.h[2], x.h[2], l1);
                l1 = FDOT2(w.h[3], x.h[3], l1);
            }
            s_l1[rr][i] = (_Float16)fmaxf(l1, 0.f);
        }
        __syncthreads();                                 // BAR7

        // ---- I: MLP layer 2 (K=256) -> px ----
        {
            int i = tid & 255, rr = tid >> 8;
            float l2 = b2v;
            #pragma unroll 4
            for (int i8=0; i8<32; i8++){
                F4H8 w; w.f = T2g4[i8*256 + i];
                F4H8 x; x.f = ((const float4*)s_l1[rr])[i8];
                l2 = FDOT2(w.h[0], x.h[0], l2);
                l2 = FDOT2(w.h[1], x.h[1], l2);
                l2 = FDOT2(w.h[2], x.h[2], l2);
                l2 = FDOT2(w.h[3], x.h[3], l2);
            }
            s_v[rr][i] = (_Float16)fmaxf(l2, 0.f);
        }
        __syncthreads();                                 // BAR8

        // ---- J: gates2 (K=512 over [px|h_post]), lane-split-K ----
        float z2i, z2f, z2g, z2o;
        {
            float ja[4][4];
            #pragma unroll
            for (int c=0;c<4;c++){
                #pragma unroll
                for (int r=0;r<4;r++) ja[c][r] = 0.f;
            }
            #pragma unroll 2
            for (int k8=0;k8<16;k8++){
                F4H8 w0,w1,w2,w3;
                w0.f = Rg4[(k8*4+0)*1024 + tid];
                w1.f = Rg4[(k8*4+1)*1024 + tid];
                w2.f = Rg4[(k8*4+2)*1024 + tid];
                w3.f = Rg4[(k8*4+3)*1024 + tid];
                #pragma unroll
                for (int r=0;r<4;r++){
                    F4H8 x; x.f = *(const float4*)&s_v[r][k8*32 + xsk];
                    #pragma unroll
                    for (int p=0;p<4;p++){
                        ja[0][r] = FDOT2(w0.h[p], x.h[p], ja[0][r]);
                        ja[1][r] = FDOT2(w1.h[p], x.h[p], ja[1][r]);
                        ja[2][r] = FDOT2(w2.h[p], x.h[p], ja[2][r]);
                        ja[3][r] = FDOT2(w3.h[p], x.h[p], ja[3][r]);
                    }
                }
            }
            #pragma unroll
            for (int c=0;c<4;c++){
                #pragma unroll
                for (int r=0;r<4;r++){
                    ja[c][r] += __shfl_xor(ja[c][r], 1);
                    ja[c][r] += __shfl_xor(ja[c][r], 2);
                }
            }
            z2i = sel4(ja[0][0],ja[0][1],ja[0][2],ja[0][3],kh) + br4.x;
            z2f = sel4(ja[1][0],ja[1][1],ja[1][2],ja[1][3],kh) + br4.y;
            z2g = sel4(ja[2][0],ja[2][1],ja[2][2],ja[2][3],kh) + br4.z;
            z2o = sel4(ja[3][0],ja[3][1],ja[3][2],ja[3][3],kh) + br4.w;
        }
        __syncthreads();                                 // BAR9

        // ---- K: cell2 for (u=cg, row=kh) ----
        {
            float ig = sigm(z2i), fg = sigm(z2f);
            float gg = tanhf_fast(z2g), og = sigm(z2o);
            c2 = fg*c2 + ig*gg;
            s_v[kh][256+cg] = (_Float16)(og*tanhf_fast(c2));
        }
        // no barrier: next read of s_v's h region is J, 8 barriers away
    }
    __syncthreads();
    {
        out[OUT_WC    + (r0+kh)*256 + cg] = c1;
        out[OUT_CPOST + (r0+kh)*256 + cg] = c2;
        out[OUT_WH    + (r0+kh)*256 + cg] = (float)s_x[kh][128+cg];
        out[OUT_HPOST + (r0+kh)*256 + cg] = (float)s_v[kh][256+cg];
    }
}

extern "C" void kernel_launch(void* const* d_in, const int* in_sizes, int n_in,
                              void* d_out, int out_size, void* d_ws, size_t ws_size,
                              hipStream_t stream) {
    const float* ext          = (const float*)d_in[0];
    const float* eps_init     = (const float*)d_in[1];
    const float* eps_seq      = (const float*)d_in[2];
    const float* eps_obs      = (const float*)d_in[3];
    const float* pp_W1        = (const float*)d_in[4];
    const float* pp_b1        = (const float*)d_in[5];
    const float* pp_W2        = (const float*)d_in[6];
    const float* pp_b2        = (const float*)d_in[7];
    const float* rnn_Wih      = (const float*)d_in[8];
    const float* rnn_Whh      = (const float*)d_in[9];
    const float* rnn_bih      = (const float*)d_in[10];
    const float* rnn_bhh      = (const float*)d_in[11];
    const float* posterior_h0 = (const float*)d_in[12];
    const float* gd_W1        = (const float*)d_in[13];
    const float* gd_b1        = (const float*)d_in[14];
    const float* gd_W2        = (const float*)d_in[15];
    const float* gd_b2        = (const float*)d_in[16];
    const float* gd_Wmu       = (const float*)d_in[17];
    const float* gd_bmu       = (const float*)d_in[18];
    const float* gd_Wls       = (const float*)d_in[19];
    const float* gd_bls       = (const float*)d_in[20];
    const float* dyn_h0       = (const float*)d_in[21];
    const float* wlstm_Wih    = (const float*)d_in[22];
    const float* wlstm_Whh    = (const float*)d_in[23];
    const float* wlstm_bih    = (const float*)d_in[24];
    const float* wlstm_bhh    = (const float*)d_in[25];
    const float* wl_W         = (const float*)d_in[26];
    const float* wl_b         = (const float*)d_in[27];
    const float* lin_W        = (const float*)d_in[28];
    const float* lin_b        = (const float*)d_in[29];
    const float* dyn_logsigma = (const float*)d_in[30];
    const float* est_logdelta = (const float*)d_in[31];
    const float* est_H        = (const float*)d_in[32];
    const float* est_bias     = (const float*)d_in[33];
    float* out = (float*)d_out;
    float* ws  = (float*)d_ws;
    _Float16* wsh = (_Float16*)d_ws;

    prep_wcat<<<1536, 256, 0, stream>>>(wlstm_Wih, wlstm_Whh, wsh);
    prep_lin <<<640,  256, 0, stream>>>(lin_W, wsh);
    prep_rnn <<<2048, 256, 0, stream>>>(rnn_Wih, rnn_Whh, wsh);
    prep_pp  <<<352,  256, 0, stream>>>(pp_W1, pp_W2, wsh);
    prep_bias<<<4,    256, 0, stream>>>(wlstm_bih, wlstm_bhh, rnn_bih, rnn_bhh, lin_b, ws);
    dblock0  <<<1,    512, 0, stream>>>(posterior_h0, gd_W1, gd_b1, gd_W2, gd_b2,
                                        gd_Wmu, gd_bmu, gd_Wls, gd_bls, ws);
    scan_fused<<<256, 1024, 0, stream>>>(ext, eps_init, eps_seq, eps_obs,
                                         dyn_h0, posterior_h0,
                                         wl_W, wl_b, dyn_logsigma,
                                         est_logdelta, est_H, est_bias,
                                         pp_b1, pp_b2, ws, out);
}